// Round 7
// baseline (110.517 us; speedup 1.0000x reference)
//
#include <hip/hip_runtime.h>
#include <hip/hip_fp16.h>
#include <math.h>

#define BATCH 8
#define NSLOT 256
#define DDIM  256
#define HID   128
#define NREL  8

typedef _Float16 half8 __attribute__((ext_vector_type(8)));
typedef float float4v __attribute__((ext_vector_type(4)));

union U8 {
  uint32_t u[4];
  _Float16 f[8];
  half8 v;
  float4 f4;
};

union H4 {
  _Float16 f[4];
  double d;
};

// d_ws layout: WT f16[256][256] at offset 0 (128 KB). No other scratch.

// ---------------------------------------------------------------------------
// Kernel 0 (validated R6): WT[c][k] = (f16) Wc[k][c], where
// Wc[k][c] = (c<128) ? W1[k][c] : W1[256+k][c-128]. k-contiguous per combined
// column c, so MFMA B-fragments are single 16-B loads. 64 blocks.
// ---------------------------------------------------------------------------
__global__ __launch_bounds__(256) void wt_kernel(
    const float* __restrict__ W1, _Float16* __restrict__ WT) {
  __shared__ float T[32][33];
  const int tx = threadIdx.x & 31;
  const int ty = threadIdx.x >> 5;  // 0..7
  const int c0 = blockIdx.x * 32, k0 = blockIdx.y * 32;
#pragma unroll
  for (int p = 0; p < 4; ++p) {
    const int k = k0 + ty + p * 8;
    const int c = c0 + tx;
    T[ty + p * 8][tx] = (c < HID) ? W1[(size_t)k * HID + c]
                                  : W1[(size_t)(DDIM + k) * HID + (c - HID)];
  }
  __syncthreads();
#pragma unroll
  for (int p = 0; p < 4; ++p) {
    const int cl = ty + p * 8;
    WT[(size_t)(c0 + cl) * 256 + k0 + tx] = (_Float16)T[tx][cl];
  }
}

// ---------------------------------------------------------------------------
// Fused kernel: per block (b, i-tile 16, j-strip 64), 256 thr / 4 waves.
//  Phase 1: stage slots rows (16 i + 64 j) -> f16 LDS (pitch 264, k-contig).
//  Phase 2: in-block proj via MFMA. A = slots tile (LDS, validated A-map);
//           B = WT cols (16-B contiguous global, validated in R6 proj).
//           P1 = i-rows @ W1[:256] + b1 ; P2 = j-rows @ W1[256:]. D-frags ->
//           LDS P1L/P2L (b16 scatter; <=2-way bank alias = free).
//  Phase 3: byte-structure-identical validated pair stage, sourcing Pi/Pj
//           from LDS: h = relu(P1+P2) in packed f16 -> mfma16x16x32 with W2
//           (8/16 cols used) -> sigmoid -> coalesced-ish stores.
// MFMA maps (HW-validated R5/R6): A[m=lane&15][k=(lane>>4)*8+u],
//  B[k=(lane>>4)*8+u][n=lane&15], D[m=(lane>>4)*4+reg][n=lane&15].
// LDS: 42.2 KB slots + 21.8 KB P = 64.0 KB -> 2 blocks/CU (grid gives 2/CU).
// ---------------------------------------------------------------------------
__global__ __launch_bounds__(256) void fused_kernel(
    const float* __restrict__ slots, const _Float16* __restrict__ WT,
    const float* __restrict__ b1, const float* __restrict__ W2,
    const float* __restrict__ b2, float* __restrict__ out) {
  __shared__ _Float16 SLI[16 * 264];  // i-rows, k-contig, pitch 264
  __shared__ _Float16 SLJ[64 * 264];  // j-rows
  __shared__ _Float16 P1L[16 * 136];  // proj_i + b1, pitch 136
  __shared__ _Float16 P2L[64 * 136];  // proj_j

  const int tid  = threadIdx.x;
  const int w    = tid >> 6;
  const int lane = tid & 63;
  const int lo16 = lane & 15;
  const int kg   = lane >> 4;  // 0..3

  const int b  = blockIdx.z;
  const int i0 = blockIdx.y * 16;
  const int j0 = blockIdx.x * 64;
  const float* Sb = slots + (size_t)b * NSLOT * DDIM;

  // ---- Phase 1: stage slots -> f16 LDS (coalesced float4 + cvt) ----
#pragma unroll
  for (int p = 0; p < 4; ++p) {      // SLI: 16 rows x 64 float4
    const int idx = tid + p * 256;
    const int r  = idx >> 6;
    const int c4 = (idx & 63) * 4;
    const float4 f = *(const float4*)(Sb + (size_t)(i0 + r) * DDIM + c4);
    H4 h;
    h.f[0] = (_Float16)f.x; h.f[1] = (_Float16)f.y;
    h.f[2] = (_Float16)f.z; h.f[3] = (_Float16)f.w;
    *(double*)&SLI[r * 264 + c4] = h.d;
  }
#pragma unroll
  for (int p = 0; p < 16; ++p) {     // SLJ: 64 rows x 64 float4
    const int idx = tid + p * 256;
    const int r  = idx >> 6;
    const int c4 = (idx & 63) * 4;
    const float4 f = *(const float4*)(Sb + (size_t)(j0 + r) * DDIM + c4);
    H4 h;
    h.f[0] = (_Float16)f.x; h.f[1] = (_Float16)f.y;
    h.f[2] = (_Float16)f.z; h.f[3] = (_Float16)f.w;
    *(double*)&SLJ[r * 264 + c4] = h.d;
  }
  __syncthreads();

  // ---- Phase 2a: P2 = SLJ @ W1[256:]  (wave w: c-tiles {2w,2w+1}, all 4 m-tiles)
#pragma unroll
  for (int t = 0; t < 2; ++t) {
    const int ntc = (2 * w + t) * 16 + lo16;  // hid col 0..127
    U8 bf[8];
#pragma unroll
    for (int ks = 0; ks < 8; ++ks)
      bf[ks].f4 = *(const float4*)(WT + (size_t)(HID + ntc) * 256 + ks * 32 + kg * 8);
#pragma unroll
    for (int mt = 0; mt < 4; ++mt) {
      float4v acc = {0.0f, 0.0f, 0.0f, 0.0f};
#pragma unroll
      for (int ks = 0; ks < 8; ++ks) {
        U8 a;
        a.f4 = *(const float4*)&SLJ[(mt * 16 + lo16) * 264 + ks * 32 + kg * 8];
        acc = __builtin_amdgcn_mfma_f32_16x16x32_f16(a.v, bf[ks].v, acc, 0, 0, 0);
      }
#pragma unroll
      for (int reg = 0; reg < 4; ++reg)
        P2L[(mt * 16 + kg * 4 + reg) * 136 + (2 * w + t) * 16 + lo16] =
            (_Float16)acc[reg];
    }
  }

  // ---- Phase 2b: P1 = SLI @ W1[:256] + b1  (wave w: c-tiles {2w,2w+1}, 1 m-tile)
#pragma unroll
  for (int t = 0; t < 2; ++t) {
    const int ntc = (2 * w + t) * 16 + lo16;  // hid col 0..127
    const float b1v = b1[ntc];
    U8 bf[8];
#pragma unroll
    for (int ks = 0; ks < 8; ++ks)
      bf[ks].f4 = *(const float4*)(WT + (size_t)ntc * 256 + ks * 32 + kg * 8);
    float4v acc = {0.0f, 0.0f, 0.0f, 0.0f};
#pragma unroll
    for (int ks = 0; ks < 8; ++ks) {
      U8 a;
      a.f4 = *(const float4*)&SLI[lo16 * 264 + ks * 32 + kg * 8];
      acc = __builtin_amdgcn_mfma_f32_16x16x32_f16(a.v, bf[ks].v, acc, 0, 0, 0);
    }
#pragma unroll
    for (int reg = 0; reg < 4; ++reg)
      P1L[(kg * 4 + reg) * 136 + (2 * w + t) * 16 + lo16] =
          (_Float16)(acc[reg] + b1v);
  }
  __syncthreads();

  // ---- Phase 3: pair stage (validated structure, LDS-sourced) ----
  const int n = lo16;
  U8 w2f[4];
#pragma unroll
  for (int kq = 0; kq < 4; ++kq) {
#pragma unroll
    for (int u = 0; u < 8; ++u) {
      const int k = kq * 32 + kg * 8 + u;
      w2f[kq].f[u] = (n < 8) ? (_Float16)W2[k * NREL + n] : (_Float16)0.0f;
    }
  }
  const float b2v = (n < 8) ? b2[n] : 0.0f;

  U8 pj[4];
#pragma unroll
  for (int kq = 0; kq < 4; ++kq) {
    pj[kq].f4 = *(const float4*)&P2L[(w * 16 + n) * 136 + kq * 32 + kg * 8];
  }

  for (int i = 0; i < 16; ++i) {
    float4v acc = {0.0f, 0.0f, 0.0f, 0.0f};
#pragma unroll
    for (int kq = 0; kq < 4; ++kq) {
      U8 pi;
      pi.f4 = *(const float4*)&P1L[i * 136 + kq * 32 + kg * 8];  // broadcast
      U8 h;
      h.v = __builtin_elementwise_max(pj[kq].v + pi.v, (half8)(_Float16)0.0f);
      acc = __builtin_amdgcn_mfma_f32_16x16x32_f16(h.v, w2f[kq].v, acc, 0, 0, 0);
    }
    if (n < 8) {
      float* obase =
          out + (((size_t)b * NSLOT + (i0 + i)) * NSLOT + (j0 + w * 16)) * NREL + n;
#pragma unroll
      for (int reg = 0; reg < 4; ++reg) {
        const int jrow = kg * 4 + reg;
        const float x = acc[reg] + b2v;
        obase[jrow * NREL] = __builtin_amdgcn_rcpf(1.0f + __expf(-x));
      }
    }
  }
}

extern "C" void kernel_launch(void* const* d_in, const int* in_sizes, int n_in,
                              void* d_out, int out_size, void* d_ws, size_t ws_size,
                              hipStream_t stream) {
  const float* slots = (const float*)d_in[0];  // [8,256,256]
  const float* W1    = (const float*)d_in[1];  // [512,128]
  const float* b1    = (const float*)d_in[2];  // [128]
  const float* W2    = (const float*)d_in[3];  // [128,8]
  const float* b2    = (const float*)d_in[4];  // [8]
  float* out   = (float*)d_out;                // [8,256,256,8]
  _Float16* WT = (_Float16*)d_ws;              // 128 KB

  wt_kernel<<<dim3(8, 8), 256, 0, stream>>>(W1, WT);
  fused_kernel<<<dim3(NSLOT / 64, NSLOT / 16, BATCH), 256, 0, stream>>>(
      slots, WT, b1, W2, b2, out);
}

// Round 8
// 92.131 us; speedup vs baseline: 1.1996x; 1.1996x over previous
//
#include <hip/hip_runtime.h>
#include <hip/hip_fp16.h>
#include <math.h>

#define BATCH 8
#define NSLOT 256
#define DDIM  256
#define HID   128
#define NREL  8

typedef _Float16 half8 __attribute__((ext_vector_type(8)));
typedef float float4v __attribute__((ext_vector_type(4)));

union U8 {
  uint32_t u[4];
  _Float16 f[8];
  half8 v;
  float4 f4;
};

union H4 {
  _Float16 f[4];
  double d;
};

// d_ws layout: WT f16[256][256] at offset 0 (128 KB).

// ---------------------------------------------------------------------------
// Kernel 0 (validated): WT[c][k] = (f16) Wc[k][c], Wc[k][c] = (c<128) ?
// W1[k][c] : W1[256+k][c-128]. k-contiguous so B-frags are 16-B loads.
// ---------------------------------------------------------------------------
__global__ __launch_bounds__(256) void wt_kernel(
    const float* __restrict__ W1, _Float16* __restrict__ WT) {
  __shared__ float T[32][33];
  const int tx = threadIdx.x & 31;
  const int ty = threadIdx.x >> 5;
  const int c0 = blockIdx.x * 32, k0 = blockIdx.y * 32;
#pragma unroll
  for (int p = 0; p < 4; ++p) {
    const int k = k0 + ty + p * 8;
    const int c = c0 + tx;
    T[ty + p * 8][tx] = (c < HID) ? W1[(size_t)k * HID + c]
                                  : W1[(size_t)(DDIM + k) * HID + (c - HID)];
  }
  __syncthreads();
#pragma unroll
  for (int p = 0; p < 4; ++p) {
    const int cl = ty + p * 8;
    WT[(size_t)(c0 + cl) * 256 + k0 + tx] = (_Float16)T[tx][cl];
  }
}

// ---------------------------------------------------------------------------
// Fused kernel v2. Block = (b, 16 i, 32 j), 1024 blocks (4/CU, ONE round),
// 256 thr / 4 waves, LDS 25.3 KB (P buffers ALIASED onto staging buffer ->
// 4+ blocks/CU resident, 16 waves/CU; was 68 KB -> 1 block/CU -> 95% stall).
//  Phase 1: stage slots (16 i + 32 j rows) -> f16 LDS, pitch 264.
//  Phase 2: proj into REGISTERS. Wave w: hid-cols {2w,2w+1}*16+lo16.
//           P1 (i-rows, 1 m-tile) 16 MFMA; P2 (j-rows, 2 m-tiles) 32 MFMA.
//  Phase 3: barrier; write P1+b1 / P2 into aliased LDS (pitch 136); barrier.
//  Phase 4: pair stage (validated): wave w -> j-window (w&1), i-half (w>>1);
//           8 i x [4x (ds_read + pk-relu + mfma16x16x32)] -> sigmoid -> store.
// MFMA maps (HW-validated R5-R7): A[m=lane&15][k=(lane>>4)*8+u],
//  B[k=(lane>>4)*8+u][n=lane&15], D[m=(lane>>4)*4+reg][n=lane&15].
// ---------------------------------------------------------------------------
__global__ __launch_bounds__(256, 4) void fused_kernel(
    const float* __restrict__ slots, const _Float16* __restrict__ WT,
    const float* __restrict__ b1, const float* __restrict__ W2,
    const float* __restrict__ b2, float* __restrict__ out) {
  __shared__ _Float16 LB[48 * 264];          // 25344 B
  _Float16* SLI = LB;                        // [16][264] staging, i-rows
  _Float16* SLJ = LB + 16 * 264;             // [32][264] staging, j-rows
  _Float16* P1L = LB;                        // [16][136] aliased after barrier
  _Float16* P2L = LB + 16 * 136;             // [32][136]

  const int tid  = threadIdx.x;
  const int w    = tid >> 6;
  const int lane = tid & 63;
  const int lo16 = lane & 15;
  const int kg   = lane >> 4;  // 0..3

  const int b  = blockIdx.z;
  const int i0 = blockIdx.y * 16;
  const int j0 = blockIdx.x * 32;
  const float* Sb = slots + (size_t)b * NSLOT * DDIM;

  // ---- Phase 1: stage slots -> f16 LDS ----
#pragma unroll
  for (int p = 0; p < 4; ++p) {  // SLI: 16 rows x 64 float4
    const int idx = tid + p * 256;
    const int r  = idx >> 6;
    const int c4 = (idx & 63) * 4;
    const float4 f = *(const float4*)(Sb + (size_t)(i0 + r) * DDIM + c4);
    H4 h;
    h.f[0] = (_Float16)f.x; h.f[1] = (_Float16)f.y;
    h.f[2] = (_Float16)f.z; h.f[3] = (_Float16)f.w;
    *(double*)&SLI[r * 264 + c4] = h.d;
  }
#pragma unroll
  for (int p = 0; p < 8; ++p) {  // SLJ: 32 rows x 64 float4
    const int idx = tid + p * 256;
    const int r  = idx >> 6;
    const int c4 = (idx & 63) * 4;
    const float4 f = *(const float4*)(Sb + (size_t)(j0 + r) * DDIM + c4);
    H4 h;
    h.f[0] = (_Float16)f.x; h.f[1] = (_Float16)f.y;
    h.f[2] = (_Float16)f.z; h.f[3] = (_Float16)f.w;
    *(double*)&SLJ[r * 264 + c4] = h.d;
  }
  __syncthreads();

  // ---- Phase 2: proj into registers ----
  float4v p1acc[2];
  float4v p2acc[2][2];
  float b1v[2];
#pragma unroll
  for (int t = 0; t < 2; ++t) {
    p1acc[t] = (float4v){0.0f, 0.0f, 0.0f, 0.0f};
    p2acc[t][0] = (float4v){0.0f, 0.0f, 0.0f, 0.0f};
    p2acc[t][1] = (float4v){0.0f, 0.0f, 0.0f, 0.0f};
  }
#pragma unroll
  for (int t = 0; t < 2; ++t) {
    const int c = (2 * w + t) * 16 + lo16;  // hid col 0..127
    b1v[t] = b1[c];
    U8 bf1[8], bf2[8];
#pragma unroll
    for (int ks = 0; ks < 8; ++ks) {
      bf1[ks].f4 = *(const float4*)(WT + (size_t)c * 256 + ks * 32 + kg * 8);
      bf2[ks].f4 = *(const float4*)(WT + (size_t)(HID + c) * 256 + ks * 32 + kg * 8);
    }
#pragma unroll
    for (int ks = 0; ks < 8; ++ks) {
      U8 a;
      a.f4 = *(const float4*)&SLI[lo16 * 264 + ks * 32 + kg * 8];
      p1acc[t] = __builtin_amdgcn_mfma_f32_16x16x32_f16(a.v, bf1[ks].v, p1acc[t], 0, 0, 0);
    }
#pragma unroll
    for (int mt = 0; mt < 2; ++mt) {
#pragma unroll
      for (int ks = 0; ks < 8; ++ks) {
        U8 a;
        a.f4 = *(const float4*)&SLJ[(mt * 16 + lo16) * 264 + ks * 32 + kg * 8];
        p2acc[t][mt] =
            __builtin_amdgcn_mfma_f32_16x16x32_f16(a.v, bf2[ks].v, p2acc[t][mt], 0, 0, 0);
      }
    }
  }
  __syncthreads();  // all staging reads complete; LB reusable

  // ---- Phase 3: write P into aliased LDS ----
#pragma unroll
  for (int t = 0; t < 2; ++t) {
    const int col = (2 * w + t) * 16 + lo16;
#pragma unroll
    for (int reg = 0; reg < 4; ++reg) {
      P1L[(kg * 4 + reg) * 136 + col] = (_Float16)(p1acc[t][reg] + b1v[t]);
      P2L[(kg * 4 + reg) * 136 + col] = (_Float16)p2acc[t][0][reg];
      P2L[(16 + kg * 4 + reg) * 136 + col] = (_Float16)p2acc[t][1][reg];
    }
  }
  __syncthreads();

  // ---- Phase 4: pair stage (validated structure) ----
  const int n  = lo16;
  const int jw = w & 1;   // j-window of 16 within the 32-j strip
  const int ih = w >> 1;  // i-half (8 i's each)

  U8 w2f[4];
#pragma unroll
  for (int kq = 0; kq < 4; ++kq) {
#pragma unroll
    for (int u = 0; u < 8; ++u) {
      const int k = kq * 32 + kg * 8 + u;
      w2f[kq].f[u] = (n < 8) ? (_Float16)W2[k * NREL + n] : (_Float16)0.0f;
    }
  }
  const float b2v = (n < 8) ? b2[n] : 0.0f;

  U8 pj[4];
#pragma unroll
  for (int kq = 0; kq < 4; ++kq) {
    pj[kq].f4 = *(const float4*)&P2L[(jw * 16 + n) * 136 + kq * 32 + kg * 8];
  }

#pragma unroll
  for (int i = 0; i < 8; ++i) {
    const int ii = ih * 8 + i;
    float4v acc = {0.0f, 0.0f, 0.0f, 0.0f};
#pragma unroll
    for (int kq = 0; kq < 4; ++kq) {
      U8 pi;
      pi.f4 = *(const float4*)&P1L[ii * 136 + kq * 32 + kg * 8];  // broadcast
      U8 h;
      h.v = __builtin_elementwise_max(pj[kq].v + pi.v, (half8)(_Float16)0.0f);
      acc = __builtin_amdgcn_mfma_f32_16x16x32_f16(h.v, w2f[kq].v, acc, 0, 0, 0);
    }
    if (n < 8) {
      float* obase =
          out + (((size_t)b * NSLOT + (i0 + ii)) * NSLOT + (j0 + jw * 16)) * NREL + n;
#pragma unroll
      for (int reg = 0; reg < 4; ++reg) {
        const int jrow = kg * 4 + reg;
        const float x = acc[reg] + b2v;
        obase[jrow * NREL] = __builtin_amdgcn_rcpf(1.0f + __expf(-x));
      }
    }
  }
}

extern "C" void kernel_launch(void* const* d_in, const int* in_sizes, int n_in,
                              void* d_out, int out_size, void* d_ws, size_t ws_size,
                              hipStream_t stream) {
  const float* slots = (const float*)d_in[0];  // [8,256,256]
  const float* W1    = (const float*)d_in[1];  // [512,128]
  const float* b1    = (const float*)d_in[2];  // [128]
  const float* W2    = (const float*)d_in[3];  // [128,8]
  const float* b2    = (const float*)d_in[4];  // [8]
  float* out   = (float*)d_out;                // [8,256,256,8]
  _Float16* WT = (_Float16*)d_ws;              // 128 KB

  wt_kernel<<<dim3(8, 8), 256, 0, stream>>>(W1, WT);
  fused_kernel<<<dim3(NSLOT / 32, NSLOT / 16, BATCH), 256, 0, stream>>>(
      slots, WT, b1, W2, b2, out);
}

// Round 9
// 86.345 us; speedup vs baseline: 1.2799x; 1.0670x over previous
//
#include <hip/hip_runtime.h>
#include <hip/hip_fp16.h>
#include <math.h>

#define BATCH 8
#define NSLOT 256
#define DDIM  256
#define HID   128
#define NREL  8

typedef _Float16 half8 __attribute__((ext_vector_type(8)));
typedef float float4v __attribute__((ext_vector_type(4)));

union U8 {
  uint32_t u[4];
  _Float16 f[8];
  half8 v;
  float4 f4;
};

// d_ws layout: WT f16[256][256] at 0 (128 KB); P f16[2048][256] at 1 MB.

// ---------------------------------------------------------------------------
// Kernel 0 (validated): WT[c][k] = (f16) Wc[k][c], Wc[k][c] = (c<128) ?
// W1[k][c] : W1[256+k][c-128]. k-contiguous so MFMA B-frags are 16-B loads.
// ---------------------------------------------------------------------------
__global__ __launch_bounds__(256) void wt_kernel(
    const float* __restrict__ W1, _Float16* __restrict__ WT) {
  __shared__ float T[32][33];
  const int tx = threadIdx.x & 31;
  const int ty = threadIdx.x >> 5;
  const int c0 = blockIdx.x * 32, k0 = blockIdx.y * 32;
#pragma unroll
  for (int p = 0; p < 4; ++p) {
    const int k = k0 + ty + p * 8;
    const int c = c0 + tx;
    T[ty + p * 8][tx] = (c < HID) ? W1[(size_t)k * HID + c]
                                  : W1[(size_t)(DDIM + k) * HID + (c - HID)];
  }
  __syncthreads();
#pragma unroll
  for (int p = 0; p < 4; ++p) {
    const int cl = ty + p * 8;
    WT[(size_t)(c0 + cl) * 256 + k0 + tx] = (_Float16)T[tx][cl];
  }
}

// ---------------------------------------------------------------------------
// projA: P computed ONCE, one wave per 16x16 tile. 2048 blocks x 64 thr.
// NO LDS, NO barriers — nothing convoys. Per wave: 16 independent float4
// slots loads (A-frags, f32->f16 cvt in reg), 8 x 16B WT loads (B-frags,
// L2-hot), 8 MFMA, bias, 4 f16 stores. b1 folded for c<128.
// MFMA maps (HW-validated R5-R8): A[m=lane&15][k=(lane>>4)*8+u],
//  B[k=(lane>>4)*8+u][n=lane&15], D[m=(lane>>4)*4+reg][n=lane&15].
// ---------------------------------------------------------------------------
__global__ __launch_bounds__(64) void projA(
    const float* __restrict__ slots, const _Float16* __restrict__ WT,
    const float* __restrict__ b1, _Float16* __restrict__ P) {
  const int lane = threadIdx.x;
  const int lo16 = lane & 15;
  const int kg   = lane >> 4;              // 0..3
  const int row0 = blockIdx.y * 16;        // global row (b*256+n), never straddles b
  const int c    = blockIdx.x * 16 + lo16; // combined hid col 0..255

  // B-fragments: 8 x 16B contiguous loads (k-contig WT).
  U8 bf[8];
#pragma unroll
  for (int ks = 0; ks < 8; ++ks)
    bf[ks].f4 = *(const float4*)(WT + (size_t)c * 256 + ks * 32 + kg * 8);

  // A-fragments from slots f32 (row = row0+lo16, k = ks*32+kg*8..+7).
  float4v acc = {0.0f, 0.0f, 0.0f, 0.0f};
  const float* srow = slots + (size_t)(row0 + lo16) * DDIM;
#pragma unroll
  for (int ks = 0; ks < 8; ++ks) {
    const float4 x0 = *(const float4*)(srow + ks * 32 + kg * 8);
    const float4 x1 = *(const float4*)(srow + ks * 32 + kg * 8 + 4);
    U8 a;
    a.f[0] = (_Float16)x0.x; a.f[1] = (_Float16)x0.y;
    a.f[2] = (_Float16)x0.z; a.f[3] = (_Float16)x0.w;
    a.f[4] = (_Float16)x1.x; a.f[5] = (_Float16)x1.y;
    a.f[6] = (_Float16)x1.z; a.f[7] = (_Float16)x1.w;
    acc = __builtin_amdgcn_mfma_f32_16x16x32_f16(a.v, bf[ks].v, acc, 0, 0, 0);
  }

  const float bias = (c < HID) ? b1[c] : 0.0f;
#pragma unroll
  for (int reg = 0; reg < 4; ++reg)
    P[(size_t)(row0 + kg * 4 + reg) * 256 + c] = (_Float16)(acc[reg] + bias);
}

// ---------------------------------------------------------------------------
// pairB (R5 verbatim, validated ~5 us): out[b,i,j,r] =
//  sigmoid( sum_k relu(P[b,i,k] + P[b,j,128+k]) * W2[k,r] + b2[r] )
// Block = 16 i x 64 j, 4 waves; wave owns a j-strip of 16. Pj frags from
// global (per-lane 16B), Pi via small LDS; W2/b2 uniform -> SGPR.
// ---------------------------------------------------------------------------
__global__ __launch_bounds__(256) void pair_kernel(
    const _Float16* __restrict__ P, const float* __restrict__ W2,
    const float* __restrict__ b2, float* __restrict__ out) {
  __shared__ uint32_t PiL[16 * 68];

  const int tid  = threadIdx.x;
  const int w    = tid >> 6;
  const int lane = tid & 63;
  const int n    = lane & 15;
  const int kg   = lane >> 4;

  const int b   = blockIdx.z;
  const int i0  = blockIdx.y * 16;
  const int j0  = blockIdx.x * 64 + w * 16;
  const _Float16* Pb = P + (size_t)b * NSLOT * 256;

  {
    const int r  = tid >> 4;
    const int ch = tid & 15;
    const float4 t = *(const float4*)(Pb + (size_t)(i0 + r) * 256 + ch * 8);
    *(float4*)&PiL[r * 68 + ch * 4] = t;
  }
  __syncthreads();

  U8 w2f[4];
#pragma unroll
  for (int kq = 0; kq < 4; ++kq) {
#pragma unroll
    for (int u = 0; u < 8; ++u) {
      const int k = kq * 32 + kg * 8 + u;
      w2f[kq].f[u] = (n < 8) ? (_Float16)W2[k * NREL + n] : (_Float16)0.0f;
    }
  }
  const float b2v = (n < 8) ? b2[n] : 0.0f;

  U8 pj[4];
#pragma unroll
  for (int kq = 0; kq < 4; ++kq) {
    pj[kq].f4 = *(const float4*)(Pb + (size_t)(j0 + n) * 256 + HID + kq * 32 + kg * 8);
  }

  for (int i = 0; i < 16; ++i) {
    float4v acc = {0.0f, 0.0f, 0.0f, 0.0f};
#pragma unroll
    for (int kq = 0; kq < 4; ++kq) {
      U8 pi;
      pi.f4 = *(const float4*)&PiL[i * 68 + kq * 16 + kg * 4];
      U8 h;
      h.v = __builtin_elementwise_max(pj[kq].v + pi.v, (half8)(_Float16)0.0f);
      acc = __builtin_amdgcn_mfma_f32_16x16x32_f16(h.v, w2f[kq].v, acc, 0, 0, 0);
    }
    if (n < 8) {
      float* obase = out + (((size_t)b * NSLOT + (i0 + i)) * NSLOT + j0) * NREL + n;
#pragma unroll
      for (int reg = 0; reg < 4; ++reg) {
        const int jrow = kg * 4 + reg;
        const float x = acc[reg] + b2v;
        obase[jrow * NREL] = __builtin_amdgcn_rcpf(1.0f + __expf(-x));
      }
    }
  }
}

extern "C" void kernel_launch(void* const* d_in, const int* in_sizes, int n_in,
                              void* d_out, int out_size, void* d_ws, size_t ws_size,
                              hipStream_t stream) {
  const float* slots = (const float*)d_in[0];  // [8,256,256]
  const float* W1    = (const float*)d_in[1];  // [512,128]
  const float* b1    = (const float*)d_in[2];  // [128]
  const float* W2    = (const float*)d_in[3];  // [128,8]
  const float* b2    = (const float*)d_in[4];  // [8]
  float* out   = (float*)d_out;                // [8,256,256,8]
  _Float16* WT = (_Float16*)d_ws;                        // 128 KB
  _Float16* P  = (_Float16*)((char*)d_ws + (1 << 20));   // 1 MB

  wt_kernel<<<dim3(8, 8), 256, 0, stream>>>(W1, WT);
  projA<<<dim3(16, 128), 64, 0, stream>>>(slots, WT, b1, P);
  pair_kernel<<<dim3(NSLOT / 64, NSLOT / 16, BATCH), 256, 0, stream>>>(P, W2, b2, out);
}

// Round 10
// 84.763 us; speedup vs baseline: 1.3038x; 1.0187x over previous
//
#include <hip/hip_runtime.h>
#include <hip/hip_fp16.h>
#include <math.h>

#define BATCH 8
#define NSLOT 256
#define DDIM  256
#define HID   128
#define NREL  8

typedef _Float16 half8 __attribute__((ext_vector_type(8)));
typedef float float4v __attribute__((ext_vector_type(4)));

union U8 {
  uint32_t u[4];
  _Float16 f[8];
  half8 v;
  float4 f4;
};

// d_ws layout: WT f16[256][256] at 0 (128 KB); W2T f16[16][128] at 512 KB;
//              P f16[2048][256] at 1 MB.

// ---------------------------------------------------------------------------
// Kernel 0 (validated + W2T prep): WT[c][k] = (f16) Wc[k][c], Wc[k][c] =
// (c<128) ? W1[k][c] : W1[256+k][c-128]. Block (0,0) additionally builds
// W2T[n][k] = (n<8) ? (f16)W2[k][n] : 0  — so pair's B-frags are 16-B loads.
// ---------------------------------------------------------------------------
__global__ __launch_bounds__(256) void wt_kernel(
    const float* __restrict__ W1, const float* __restrict__ W2,
    _Float16* __restrict__ WT, _Float16* __restrict__ W2T) {
  __shared__ float T[32][33];
  const int tx = threadIdx.x & 31;
  const int ty = threadIdx.x >> 5;
  const int c0 = blockIdx.x * 32, k0 = blockIdx.y * 32;
#pragma unroll
  for (int p = 0; p < 4; ++p) {
    const int k = k0 + ty + p * 8;
    const int c = c0 + tx;
    T[ty + p * 8][tx] = (c < HID) ? W1[(size_t)k * HID + c]
                                  : W1[(size_t)(DDIM + k) * HID + (c - HID)];
  }
  __syncthreads();
#pragma unroll
  for (int p = 0; p < 4; ++p) {
    const int cl = ty + p * 8;
    WT[(size_t)(c0 + cl) * 256 + k0 + tx] = (_Float16)T[tx][cl];
  }
  if (blockIdx.x == 0 && blockIdx.y == 0) {
#pragma unroll
    for (int p = 0; p < 8; ++p) {
      const int idx = threadIdx.x + p * 256;  // 0..2047
      const int n = idx >> 7, k = idx & 127;
      W2T[n * 128 + k] = (n < 8) ? (_Float16)W2[k * NREL + n] : (_Float16)0.0f;
    }
  }
}

// ---------------------------------------------------------------------------
// projA (validated R9): P computed once, one wave per 16x16 tile. 2048 blocks
// x 64 thr, no LDS/barriers. 16 slots float4 loads (cvt f16) + 8 WT B-frags
// + 8 MFMA + bias + stores.
// MFMA maps (HW-validated R5-R9): A[m=lane&15][k=(lane>>4)*8+u],
//  B[k=(lane>>4)*8+u][n=lane&15], D[m=(lane>>4)*4+reg][n=lane&15].
// ---------------------------------------------------------------------------
__global__ __launch_bounds__(64) void projA(
    const float* __restrict__ slots, const _Float16* __restrict__ WT,
    const float* __restrict__ b1, _Float16* __restrict__ P) {
  const int lane = threadIdx.x;
  const int lo16 = lane & 15;
  const int kg   = lane >> 4;
  const int row0 = blockIdx.y * 16;
  const int c    = blockIdx.x * 16 + lo16;

  U8 bf[8];
#pragma unroll
  for (int ks = 0; ks < 8; ++ks)
    bf[ks].f4 = *(const float4*)(WT + (size_t)c * 256 + ks * 32 + kg * 8);

  float4v acc = {0.0f, 0.0f, 0.0f, 0.0f};
  const float* srow = slots + (size_t)(row0 + lo16) * DDIM;
#pragma unroll
  for (int ks = 0; ks < 8; ++ks) {
    const float4 x0 = *(const float4*)(srow + ks * 32 + kg * 8);
    const float4 x1 = *(const float4*)(srow + ks * 32 + kg * 8 + 4);
    U8 a;
    a.f[0] = (_Float16)x0.x; a.f[1] = (_Float16)x0.y;
    a.f[2] = (_Float16)x0.z; a.f[3] = (_Float16)x0.w;
    a.f[4] = (_Float16)x1.x; a.f[5] = (_Float16)x1.y;
    a.f[6] = (_Float16)x1.z; a.f[7] = (_Float16)x1.w;
    acc = __builtin_amdgcn_mfma_f32_16x16x32_f16(a.v, bf[ks].v, acc, 0, 0, 0);
  }

  const float bias = (c < HID) ? b1[c] : 0.0f;
#pragma unroll
  for (int reg = 0; reg < 4; ++reg)
    P[(size_t)(row0 + kg * 4 + reg) * 256 + c] = (_Float16)(acc[reg] + bias);
}

// ---------------------------------------------------------------------------
// pair v4: validated R5 math; i-tile 8 (grid 1024 blocks -> 4096 waves =
// 4 waves/SIMD, 2x latency tolerance) and W2T 16-B B-frag loads (was 32
// per-lane dword loads of W2).
// ---------------------------------------------------------------------------
__global__ __launch_bounds__(256) void pair_kernel(
    const _Float16* __restrict__ P, const _Float16* __restrict__ W2T,
    const float* __restrict__ b2, float* __restrict__ out) {
  __shared__ uint32_t PiL[8 * 68];

  const int tid  = threadIdx.x;
  const int w    = tid >> 6;
  const int lane = tid & 63;
  const int n    = lane & 15;
  const int kg   = lane >> 4;

  const int b   = blockIdx.z;
  const int i0  = blockIdx.y * 8;
  const int j0  = blockIdx.x * 64 + w * 16;
  const _Float16* Pb = P + (size_t)b * NSLOT * 256;

  if (tid < 128) {  // stage Pi: 8 rows x 128 f16
    const int r  = tid >> 4;
    const int ch = tid & 15;
    const float4 t = *(const float4*)(Pb + (size_t)(i0 + r) * 256 + ch * 8);
    *(float4*)&PiL[r * 68 + ch * 4] = t;
  }

  U8 w2f[4];
#pragma unroll
  for (int kq = 0; kq < 4; ++kq)
    w2f[kq].f4 = *(const float4*)(W2T + n * 128 + kq * 32 + kg * 8);

  const float b2v = (n < 8) ? b2[n] : 0.0f;

  U8 pj[4];
#pragma unroll
  for (int kq = 0; kq < 4; ++kq)
    pj[kq].f4 = *(const float4*)(Pb + (size_t)(j0 + n) * 256 + HID + kq * 32 + kg * 8);

  __syncthreads();

#pragma unroll
  for (int i = 0; i < 8; ++i) {
    float4v acc = {0.0f, 0.0f, 0.0f, 0.0f};
#pragma unroll
    for (int kq = 0; kq < 4; ++kq) {
      U8 pi;
      pi.f4 = *(const float4*)&PiL[i * 68 + kq * 16 + kg * 4];  // broadcast
      U8 h;
      h.v = __builtin_elementwise_max(pj[kq].v + pi.v, (half8)(_Float16)0.0f);
      acc = __builtin_amdgcn_mfma_f32_16x16x32_f16(h.v, w2f[kq].v, acc, 0, 0, 0);
    }
    if (n < 8) {
      float* obase = out + (((size_t)b * NSLOT + (i0 + i)) * NSLOT + j0) * NREL + n;
#pragma unroll
      for (int reg = 0; reg < 4; ++reg) {
        const int jrow = kg * 4 + reg;
        const float x = acc[reg] + b2v;
        obase[jrow * NREL] = __builtin_amdgcn_rcpf(1.0f + __expf(-x));
      }
    }
  }
}

extern "C" void kernel_launch(void* const* d_in, const int* in_sizes, int n_in,
                              void* d_out, int out_size, void* d_ws, size_t ws_size,
                              hipStream_t stream) {
  const float* slots = (const float*)d_in[0];  // [8,256,256]
  const float* W1    = (const float*)d_in[1];  // [512,128]
  const float* b1    = (const float*)d_in[2];  // [128]
  const float* W2    = (const float*)d_in[3];  // [128,8]
  const float* b2    = (const float*)d_in[4];  // [8]
  float* out    = (float*)d_out;               // [8,256,256,8]
  _Float16* WT  = (_Float16*)d_ws;                         // 128 KB
  _Float16* W2T = (_Float16*)((char*)d_ws + (512 << 10));  // 4 KB
  _Float16* P   = (_Float16*)((char*)d_ws + (1 << 20));    // 1 MB

  wt_kernel<<<dim3(8, 8), 256, 0, stream>>>(W1, W2, WT, W2T);
  projA<<<dim3(16, 128), 64, 0, stream>>>(slots, WT, b1, P);
  pair_kernel<<<dim3(NSLOT / 64, NSLOT / 8, BATCH), 256, 0, stream>>>(P, W2T, b2, out);
}